// Round 1
// baseline (662.066 us; speedup 1.0000x reference)
//
#include <hip/hip_runtime.h>

#define NB 16
#define TT 6000
#define HH 256
#define CC 105
#define MIN_GAP_ 19
#define REF_GAP_ 9

// GEMM tile
#define BM 64
#define BK 64
#define APAD 68    // 64 + 4 pad: breaks write bank conflicts, keeps float4 alignment
#define NPAD 112

__global__ __launch_bounds__(256) void gemm_kernel(
    const float* __restrict__ feat, const float* __restrict__ W,
    const float* __restrict__ bias, float* __restrict__ out0,
    float* __restrict__ out1) {
  __shared__ __align__(16) float aS[BK][APAD];   // [k][m]
  __shared__ __align__(16) float wS[BK][NPAD];   // [k][c]
  const int tid = threadIdx.x;
  const int row0 = blockIdx.x * BM;
  const int ty = tid >> 4;   // 0..15 -> rows ty*4..ty*4+3
  const int tx = tid & 15;   // 0..15 -> channels tx*7..tx*7+6

  float acc[4][7];
#pragma unroll
  for (int i = 0; i < 4; i++)
#pragma unroll
    for (int j = 0; j < 7; j++) acc[i][j] = 0.f;

  const int r  = tid >> 2;   // 0..63 staging row
  const int kq = tid & 3;

  for (int k0 = 0; k0 < HH; k0 += BK) {
    // stage A tile (64 rows x 64 k), transposed to k-major
#pragma unroll
    for (int l = 0; l < 4; l++) {
      const int k4 = kq + 4 * l;   // 0..15
      const float4 v = *reinterpret_cast<const float4*>(
          &feat[(size_t)(row0 + r) * HH + k0 + k4 * 4]);
      aS[k4 * 4 + 0][r] = v.x;
      aS[k4 * 4 + 1][r] = v.y;
      aS[k4 * 4 + 2][r] = v.z;
      aS[k4 * 4 + 3][r] = v.w;
    }
    // stage W tile (105 ch x 64 k), transposed to k-major
    for (int idx = tid; idx < CC * 16; idx += 256) {
      const int c  = idx >> 4;
      const int k4 = idx & 15;
      const float4 v = *reinterpret_cast<const float4*>(
          &W[(size_t)c * HH + k0 + k4 * 4]);
      wS[k4 * 4 + 0][c] = v.x;
      wS[k4 * 4 + 1][c] = v.y;
      wS[k4 * 4 + 2][c] = v.z;
      wS[k4 * 4 + 3][c] = v.w;
    }
    __syncthreads();
#pragma unroll 8
    for (int k = 0; k < BK; k++) {
      const float4 a = *reinterpret_cast<const float4*>(&aS[k][ty * 4]);
      const float av[4] = {a.x, a.y, a.z, a.w};
#pragma unroll
      for (int jj = 0; jj < 7; jj++) {
        const float w = wS[k][tx * 7 + jj];
#pragma unroll
        for (int i = 0; i < 4; i++) acc[i][jj] = fmaf(av[i], w, acc[i][jj]);
      }
    }
    __syncthreads();
  }

#pragma unroll
  for (int i = 0; i < 4; i++) {
    const int row = row0 + ty * 4 + i;
#pragma unroll
    for (int jj = 0; jj < 7; jj++) {
      const int c = tx * 7 + jj;
      if (c < CC) {
        const float v = acc[i][jj] + bias[c];
        if (c == 0) {
          out0[row] = fminf(fmaxf(v, -16.f), 16.f);
        } else {
          out1[(size_t)row * (CC - 1) + (c - 1)] = v;
        }
      }
    }
  }
}

// One block per batch row. Thread 0 does the inherently-serial scans;
// all threads cooperate on LDS loads and the final masked write.
__global__ __launch_bounds__(256) void phase_kernel(
    const float* __restrict__ bd_logits,   // clipped ch-0 logits (= out0)
    const int* __restrict__ word_bd,
    const float* __restrict__ non_padding,
    float* __restrict__ out2) {
  __shared__ float lbuf[TT];   // phase1: logits; phase2: ref (word_bd as float)
  __shared__ int res[TT + 1];  // index TT = trash slot
  __shared__ int L_sh;
  const int b = blockIdx.x;
  const int tid = threadIdx.x;
  if (tid == 0) L_sh = 0;
  __syncthreads();

  int cnt = 0;
  for (int j = tid; j < TT; j += 256) {
    lbuf[j] = bd_logits[(size_t)b * TT + j];
    cnt += (non_padding[(size_t)b * TT + j] != 0.f) ? 1 : 0;
  }
  atomicAdd(&L_sh, cnt);
  for (int j = tid; j <= TT; j += 256) res[j] = 0;
  __syncthreads();

  if (tid == 0) {
    // ---- phase 1: run detection + argmax + merge ----
    int last = -1, rmi = 0;
    float rmv = -1e30f;
    bool in_run = false;
    for (int j0 = 0; j0 < TT; j0 += 8) {
      const float4 v0 = *reinterpret_cast<const float4*>(&lbuf[j0]);
      const float4 v1 = *reinterpret_cast<const float4*>(&lbuf[j0 + 4]);
      const float l[8] = {v0.x, v0.y, v0.z, v0.w, v1.x, v1.y, v1.z, v1.w};
#pragma unroll
      for (int q = 0; q < 8; q++) {
        const int j = j0 + q;
        const float lj = l[q];
        if (lj > 0.f) {               // sigmoid(l) > 0.5  <=>  l > 0
          if (!in_run) { in_run = true; rmv = lj; rmi = j; }
          else if (lj > rmv) { rmv = lj; rmi = j; }
        } else if (in_run) {
          in_run = false;
          int bd_idx = rmi;
          if (last > 0 && (bd_idx - last) < MIN_GAP_) {
            const int s = bd_idx + last;
            const int h = s >> 1;
            bd_idx = (s & 1) ? (h + (h & 1)) : h;   // jnp.round: ties to even
            res[last] = 0;
          }
          res[bd_idx] = 1;
          last = bd_idx;
        }
      }
    }
  }
  __syncthreads();

  // reload buffer with word_bd (phase1 no longer needs logits)
  for (int j = tid; j < TT; j += 256)
    lbuf[j] = (float)word_bd[(size_t)b * TT + j];
  __syncthreads();

  if (tid == 0) {
    // ---- phase 2: align to word boundaries ----
    for (int j0 = 0; j0 < TT; j0 += 8) {
      const float4 r0 = *reinterpret_cast<const float4*>(&lbuf[j0]);
      const float4 r1 = *reinterpret_cast<const float4*>(&lbuf[j0 + 4]);
      if (r0.x + r0.y + r0.z + r0.w + r1.x + r1.y + r1.z + r1.w == 0.f)
        continue;
      const float rv[8] = {r0.x, r0.y, r0.z, r0.w, r1.x, r1.y, r1.z, r1.w};
#pragma unroll
      for (int q = 0; q < 8; q++) {
        if (rv[q] != 1.f) continue;
        const int j = j0 + q;
        const int lo = (j - REF_GAP_ < 0) ? 0 : j - REF_GAP_;
        const int hi = (j + REF_GAP_ - 1 > TT - 1) ? TT - 1 : j + REF_GAP_ - 1;
        int seg = 0;
        for (int w = lo; w <= hi; w++) seg += res[w];
        if (seg == 0) {
          res[j] = 1;
        } else if (seg == 1) {
          if (res[j] != 1) {
            for (int w = lo; w <= hi; w++) res[w] = (lbuf[w] == 1.f) ? 1 : 0;
          }
        } else {  // seg > 1
          int zidx = -1;
          for (int k = 1; k <= REF_GAP_; k++) {
            const int li = (j - k < 0) ? 0 : j - k;
            const int ri = (j + k > TT - 1) ? TT - 1 : j + k;
            if (res[li] == 1 && lbuf[li] != 1.f) { zidx = li; break; }
            if (res[ri] == 1 && lbuf[ri] != 1.f) { zidx = ri; break; }
          }
          if (zidx >= 0) res[zidx] = 0;
          res[j] = 1;
        }
      }
    }
  }
  __syncthreads();

  const int L = L_sh;
  for (int t = tid; t < TT; t += 256)
    out2[(size_t)b * TT + t] = (t >= 1 && t < L - 1) ? (float)res[t] : 0.f;
}

extern "C" void kernel_launch(void* const* d_in, const int* in_sizes, int n_in,
                              void* d_out, int out_size, void* d_ws, size_t ws_size,
                              hipStream_t stream) {
  const float* feat        = (const float*)d_in[0];
  const int*   word_bd     = (const int*)d_in[1];
  const float* non_padding = (const float*)d_in[2];
  const float* W           = (const float*)d_in[3];
  const float* bias        = (const float*)d_in[4];

  float* out  = (float*)d_out;
  float* out0 = out;                                        // (B,T) clipped ch0
  float* out1 = out + (size_t)NB * TT;                      // (B,T,104)
  float* out2 = out + (size_t)NB * TT + (size_t)NB * TT * (CC - 1);  // (B,T) pred

  hipLaunchKernelGGL(gemm_kernel, dim3((NB * TT) / BM), dim3(256), 0, stream,
                     feat, W, bias, out0, out1);
  hipLaunchKernelGGL(phase_kernel, dim3(NB), dim3(256), 0, stream,
                     out0, word_bd, non_padding, out2);
}

// Round 2
// 253.704 us; speedup vs baseline: 2.6096x; 2.6096x over previous
//
#include <hip/hip_runtime.h>

#define NB 16
#define TT 6000
#define HH 256
#define CC 105
#define MIN_GAP_ 19
#define REF_GAP_ 9

// GEMM tile
#define BM 64
#define BK 64
#define APAD 68
#define NPAD 112

__global__ __launch_bounds__(256) void gemm_kernel(
    const float* __restrict__ feat, const float* __restrict__ W,
    const float* __restrict__ bias, float* __restrict__ out0,
    float* __restrict__ out1) {
  __shared__ __align__(16) float aS[BK][APAD];   // [k][m]
  __shared__ __align__(16) float wS[BK][NPAD];   // [k][c]
  const int tid = threadIdx.x;
  const int row0 = blockIdx.x * BM;
  const int ty = tid >> 4;
  const int tx = tid & 15;

  float acc[4][7];
#pragma unroll
  for (int i = 0; i < 4; i++)
#pragma unroll
    for (int j = 0; j < 7; j++) acc[i][j] = 0.f;

  const int r  = tid >> 2;
  const int kq = tid & 3;

  for (int k0 = 0; k0 < HH; k0 += BK) {
#pragma unroll
    for (int l = 0; l < 4; l++) {
      const int k4 = kq + 4 * l;
      const float4 v = *reinterpret_cast<const float4*>(
          &feat[(size_t)(row0 + r) * HH + k0 + k4 * 4]);
      aS[k4 * 4 + 0][r] = v.x;
      aS[k4 * 4 + 1][r] = v.y;
      aS[k4 * 4 + 2][r] = v.z;
      aS[k4 * 4 + 3][r] = v.w;
    }
    for (int idx = tid; idx < CC * 16; idx += 256) {
      const int c  = idx >> 4;
      const int k4 = idx & 15;
      const float4 v = *reinterpret_cast<const float4*>(
          &W[(size_t)c * HH + k0 + k4 * 4]);
      wS[k4 * 4 + 0][c] = v.x;
      wS[k4 * 4 + 1][c] = v.y;
      wS[k4 * 4 + 2][c] = v.z;
      wS[k4 * 4 + 3][c] = v.w;
    }
    __syncthreads();
#pragma unroll 8
    for (int k = 0; k < BK; k++) {
      const float4 a = *reinterpret_cast<const float4*>(&aS[k][ty * 4]);
      const float av[4] = {a.x, a.y, a.z, a.w};
#pragma unroll
      for (int jj = 0; jj < 7; jj++) {
        const float w = wS[k][tx * 7 + jj];
#pragma unroll
        for (int i = 0; i < 4; i++) acc[i][jj] = fmaf(av[i], w, acc[i][jj]);
      }
    }
    __syncthreads();
  }

#pragma unroll
  for (int i = 0; i < 4; i++) {
    const int row = row0 + ty * 4 + i;
#pragma unroll
    for (int jj = 0; jj < 7; jj++) {
      const int c = tx * 7 + jj;
      if (c < CC) {
        const float v = acc[i][jj] + bias[c];
        if (c == 0) {
          out0[row] = fminf(fmaxf(v, -16.f), 16.f);
        } else {
          out1[(size_t)row * (CC - 1) + (c - 1)] = v;
        }
      }
    }
  }
}

// One block per batch. Parallel run-detect/argmax + compaction, serial merge
// chain over ~1500 compacted runs (thread 0, int4-prefetched), parallel
// phase 2 (word boundaries >=25 apart; each touches only [j-9, j+9]).
#define STRIPE 24   // ceil(6000/256) -> threads 0..249 own 24 positions each

__global__ __launch_bounds__(256) void phase_kernel(
    const float* __restrict__ bd_logits,   // clipped ch-0 logits (= out0)
    const int* __restrict__ word_bd,
    const float* __restrict__ non_padding,
    float* __restrict__ out2) {
  __shared__ __align__(16) float lbuf[TT];        // clipped logits
  __shared__ __align__(16) int   wbuf[TT];        // word_bd
  __shared__ __align__(16) int   res[TT];
  __shared__ unsigned char bdm[TT + 4];           // bd mask
  __shared__ __align__(16) int   runIdx[3072 + 8]; // argmax idx per run, ordered
  __shared__ int scn[256];
  __shared__ int L_sh, nruns_sh;

  const int b = blockIdx.x;
  const int tid = threadIdx.x;
  if (tid == 0) L_sh = 0;
  __syncthreads();

  int cnt_np = 0;
  for (int j = tid; j < TT; j += 256) {
    const float l = bd_logits[(size_t)b * TT + j];
    lbuf[j] = l;
    bdm[j] = (l > 0.f) ? 1 : 0;        // sigmoid(l) > 0.5  <=>  l > 0
    wbuf[j] = word_bd[(size_t)b * TT + j];
    res[j] = 0;
    cnt_np += (non_padding[(size_t)b * TT + j] != 0.f) ? 1 : 0;
  }
  atomicAdd(&L_sh, cnt_np);
  __syncthreads();

  // ---- phase 1a: count run-ends per stripe ----
  const int s0 = tid * STRIPE;
  const int s1 = min(TT - 1, s0 + STRIPE - 1);   // e <= T-1 (run at T-1 never finalizes)
  int cnt = 0;
  if (s0 < TT) {
    for (int e = max(1, s0); e <= s1; e++)
      cnt += (!bdm[e] && bdm[e - 1]) ? 1 : 0;
  }
  // inclusive scan across 256 threads
  scn[tid] = cnt;
  __syncthreads();
  for (int off = 1; off < 256; off <<= 1) {
    const int t = (tid >= off) ? scn[tid - off] : 0;
    __syncthreads();
    scn[tid] += t;
    __syncthreads();
  }
  if (tid == 255) nruns_sh = scn[255];
  int slot = scn[tid] - cnt;   // exclusive base
  __syncthreads();

  // ---- phase 1b: emit run argmax indices in position order ----
  if (s0 < TT) {
    for (int e = max(1, s0); e <= s1; e++) {
      if (!bdm[e] && bdm[e - 1]) {
        int i = e - 1;
        float mv = lbuf[i];
        int mi = i;
        while (i > 0 && bdm[i - 1]) {   // walk back; >= keeps earliest max
          --i;
          const float v = lbuf[i];
          if (v >= mv) { mv = v; mi = i; }
        }
        runIdx[slot++] = mi;
      }
    }
  }
  __syncthreads();

  // ---- phase 1c: serial merge chain over compacted runs (thread 0) ----
  if (tid == 0) {
    const int n = nruns_sh;
    // pad so int4 reads past n are in-bounds
    for (int p = n; p < ((n + 7) & ~7) + 8; p++) runIdx[p] = 0;
    int last = -1;
    int4 c0 = *reinterpret_cast<int4*>(&runIdx[0]);
    int4 c1 = *reinterpret_cast<int4*>(&runIdx[4]);
    for (int i0 = 0; i0 < n; i0 += 8) {
      const int4 n0 = *reinterpret_cast<int4*>(&runIdx[i0 + 8]);
      const int4 n1 = *reinterpret_cast<int4*>(&runIdx[i0 + 12]);
      const int vals[8] = {c0.x, c0.y, c0.z, c0.w, c1.x, c1.y, c1.z, c1.w};
      const int m = (n - i0 < 8) ? (n - i0) : 8;
#pragma unroll 8
      for (int q = 0; q < 8; q++) {
        if (q >= m) break;
        int bd_idx = vals[q];
        if (last > 0 && (bd_idx - last) < MIN_GAP_) {
          const int s = bd_idx + last;
          const int h = s >> 1;
          bd_idx = (s & 1) ? (h + (h & 1)) : h;   // round half to even
          res[last] = 0;
        }
        res[bd_idx] = 1;
        last = bd_idx;
      }
      c0 = n0;
      c1 = n1;
    }
  }
  __syncthreads();

  // ---- phase 2: parallel over word boundaries (disjoint +-9 windows) ----
  for (int j = tid; j < TT; j += 256) {
    if (wbuf[j] != 1) continue;
    const int lo = (j - REF_GAP_ < 0) ? 0 : j - REF_GAP_;
    const int hi = (j + REF_GAP_ - 1 > TT - 1) ? TT - 1 : j + REF_GAP_ - 1;
    int seg = 0;
    for (int w = lo; w <= hi; w++) seg += res[w];
    if (seg == 0) {
      res[j] = 1;
    } else if (seg == 1) {
      if (res[j] != 1) {
        for (int w = lo; w <= hi; w++) res[w] = wbuf[w];
      }
    } else {
      int zidx = -1;
      for (int k = 1; k <= REF_GAP_; k++) {
        const int li = (j - k < 0) ? 0 : j - k;
        const int ri = (j + k > TT - 1) ? TT - 1 : j + k;
        if (res[li] == 1 && wbuf[li] != 1) { zidx = li; break; }
        if (res[ri] == 1 && wbuf[ri] != 1) { zidx = ri; break; }
      }
      if (zidx >= 0) res[zidx] = 0;
      res[j] = 1;
    }
  }
  __syncthreads();

  const int L = L_sh;
  for (int t = tid; t < TT; t += 256)
    out2[(size_t)b * TT + t] = (t >= 1 && t < L - 1) ? (float)res[t] : 0.f;
}

extern "C" void kernel_launch(void* const* d_in, const int* in_sizes, int n_in,
                              void* d_out, int out_size, void* d_ws, size_t ws_size,
                              hipStream_t stream) {
  const float* feat        = (const float*)d_in[0];
  const int*   word_bd     = (const int*)d_in[1];
  const float* non_padding = (const float*)d_in[2];
  const float* W           = (const float*)d_in[3];
  const float* bias        = (const float*)d_in[4];

  float* out  = (float*)d_out;
  float* out0 = out;
  float* out1 = out + (size_t)NB * TT;
  float* out2 = out + (size_t)NB * TT + (size_t)NB * TT * (CC - 1);

  hipLaunchKernelGGL(gemm_kernel, dim3((NB * TT) / BM), dim3(256), 0, stream,
                     feat, W, bias, out0, out1);
  hipLaunchKernelGGL(phase_kernel, dim3(NB), dim3(256), 0, stream,
                     out0, word_bd, non_padding, out2);
}